// Round 12
// baseline (291.824 us; speedup 1.0000x reference)
//
#include <hip/hip_runtime.h>
#include <hip/hip_bf16.h>
#include <math.h>

#define NN 8192
#define EMB 64
#define H1D 512
#define NB 4096

typedef __bf16 bf16x8 __attribute__((ext_vector_type(8)));
typedef float f32x4 __attribute__((ext_vector_type(4)));
typedef unsigned short u16x8 __attribute__((ext_vector_type(8)));
typedef unsigned short u16x4 __attribute__((ext_vector_type(4)));

__device__ __forceinline__ unsigned short f2bf(float f) {
    return __bfloat16_as_ushort(__float2bfloat16(f));
}

__device__ __forceinline__ void gload16(const void* g, void* l) {
    __builtin_amdgcn_global_load_lds(
        (const __attribute__((address_space(1))) void*)g,
        (__attribute__((address_space(3))) void*)l, 16, 0, 0);
}

// ---------------- K0: extract diagonal ----------------
__global__ void k_diag(const float* __restrict__ state, float* __restrict__ diag) {
    int i = blockIdx.x * blockDim.x + threadIdx.x;
    if (i < NN) diag[i] = state[(size_t)i * NN + i];
}

// ---------------- fused: state fp32 -> stateb bf16, + rowdot s[i] ----------------
__global__ __launch_bounds__(256) void k_convert(const float* __restrict__ state,
                                                 const float* __restrict__ diag,
                                                 unsigned short* __restrict__ stateb,
                                                 float* __restrict__ s) {
    int row = blockIdx.x;
    int tid = threadIdx.x;
    const float4* st4 = (const float4*)(state + (size_t)row * NN);
    const float4* dg4 = (const float4*)diag;
    unsigned short* drow = stateb + (size_t)row * NN;
    float acc = 0.f;
#pragma unroll
    for (int t = 0; t < 8; ++t) {
        int f = t * 256 + tid;
        float4 a = st4[f], d = dg4[f];
        acc += a.x * d.x + a.y * d.y + a.z * d.z + a.w * d.w;
        u16x4 o;
        o[0] = f2bf(a.x); o[1] = f2bf(a.y); o[2] = f2bf(a.z); o[3] = f2bf(a.w);
        *(u16x4*)&drow[f * 4] = o;
    }
#pragma unroll
    for (int m = 32; m >= 1; m >>= 1) acc += __shfl_xor(acc, m);
    __shared__ float red[4];
    if ((tid & 63) == 0) red[tid >> 6] = acc;
    __syncthreads();
    if (tid == 0) {
        float tot = red[0] + red[1] + red[2] + red[3];
        float d = diag[row];
        s[row] = tot - d * d;
    }
}

// ---------------- fw1 [16512][512] -> fw1t bf16 [512][16512] ----------------
__global__ __launch_bounds__(256) void k_tr_fw1(const float* __restrict__ fw1,
                                                unsigned short* __restrict__ fw1t) {
    __shared__ float t[64][65];
    int kb = blockIdx.x * 64, nb = blockIdx.y * 64;
    int tid = threadIdx.x;
#pragma unroll
    for (int i = 0; i < 4; ++i) {
        int lin = i * 256 + tid;
        int r = lin >> 4, c4 = (lin & 15) << 2;
        float4 v = *(const float4*)&fw1[(size_t)(kb + r) * 512 + nb + c4];
        t[r][c4] = v.x; t[r][c4 + 1] = v.y; t[r][c4 + 2] = v.z; t[r][c4 + 3] = v.w;
    }
    __syncthreads();
#pragma unroll
    for (int i = 0; i < 4; ++i) {
        int lin = i * 256 + tid;
        int n = lin >> 4, k4 = (lin & 15) << 2;
        u16x4 o;
        o[0] = f2bf(t[k4 + 0][n]); o[1] = f2bf(t[k4 + 1][n]);
        o[2] = f2bf(t[k4 + 2][n]); o[3] = f2bf(t[k4 + 3][n]);
        *(u16x4*)&fw1t[(size_t)(nb + n) * 16512 + kb + k4] = o;
    }
}

// ---------------- generic W [K][N] fp32 -> Wt bf16 [N][K] (dims % 64 == 0) ----------------
__global__ __launch_bounds__(256) void k_tr_w(const float* __restrict__ W,
                                              unsigned short* __restrict__ Wt,
                                              int K, int N) {
    __shared__ float t[64][65];
    int kb = blockIdx.x * 64, nb = blockIdx.y * 64;
    int tid = threadIdx.x;
#pragma unroll
    for (int i = 0; i < 4; ++i) {
        int lin = i * 256 + tid;
        int r = lin >> 4, c4 = (lin & 15) << 2;
        float4 v = *(const float4*)&W[(size_t)(kb + r) * N + nb + c4];
        t[r][c4] = v.x; t[r][c4 + 1] = v.y; t[r][c4 + 2] = v.z; t[r][c4 + 3] = v.w;
    }
    __syncthreads();
#pragma unroll
    for (int i = 0; i < 4; ++i) {
        int lin = i * 256 + tid;
        int n = lin >> 4, k4 = (lin & 15) << 2;
        u16x4 o;
        o[0] = f2bf(t[k4 + 0][n]); o[1] = f2bf(t[k4 + 1][n]);
        o[2] = f2bf(t[k4 + 2][n]); o[3] = f2bf(t[k4 + 3][n]);
        *(u16x4*)&Wt[(size_t)(nb + n) * K + kb + k4] = o;
    }
}

// ---------------- q [8192][64] fp32 -> qbT bf16 [64][8192] ----------------
__global__ __launch_bounds__(256) void k_tr_q(const float* __restrict__ q,
                                              unsigned short* __restrict__ qbT) {
    __shared__ float t[64][65];
    int kb = blockIdx.x * 64;
    int tid = threadIdx.x;
#pragma unroll
    for (int i = 0; i < 4; ++i) {
        int lin = i * 256 + tid;
        int r = lin >> 4, c4 = (lin & 15) << 2;
        float4 v = *(const float4*)&q[(size_t)(kb + r) * 64 + c4];
        t[r][c4] = v.x; t[r][c4 + 1] = v.y; t[r][c4 + 2] = v.z; t[r][c4 + 3] = v.w;
    }
    __syncthreads();
#pragma unroll
    for (int i = 0; i < 4; ++i) {
        int lin = i * 256 + tid;
        int c = lin >> 4, k4 = (lin & 15) << 2;
        u16x4 o;
        o[0] = f2bf(t[k4 + 0][c]); o[1] = f2bf(t[k4 + 1][c]);
        o[2] = f2bf(t[k4 + 2][c]); o[3] = f2bf(t[k4 + 3][c]);
        *(u16x4*)&qbT[(size_t)c * 8192 + kb + k4] = o;
    }
}

// ---------------- K1 (fallback): s[i] = sum_k adj[i,k]*diag[k] ----------------
__global__ __launch_bounds__(256) void k_rowdot(const float* __restrict__ state,
                                                const float* __restrict__ diag,
                                                float* __restrict__ s) {
    int row = blockIdx.x;
    int tid = threadIdx.x;
    const float4* st4 = (const float4*)(state + (size_t)row * NN);
    const float4* dg4 = (const float4*)diag;
    float acc = 0.f;
#pragma unroll
    for (int t = 0; t < 8; ++t) {
        int f = t * 256 + tid;
        float4 a = st4[f], d = dg4[f];
        acc += a.x * d.x + a.y * d.y + a.z * d.z + a.w * d.w;
    }
#pragma unroll
    for (int m = 32; m >= 1; m >>= 1) acc += __shfl_xor(acc, m);
    __shared__ float red[4];
    if ((tid & 63) == 0) red[tid >> 6] = acc;
    __syncthreads();
    if (tid == 0) {
        float tot = red[0] + red[1] + red[2] + red[3];
        float d = diag[row];
        s[row] = tot - d * d;
    }
}

// ---------------- K2: q[k][c] = sum_j relu(s[k]*gw1[j]+gb1[j]) * gw2[j][c] ----------------
__global__ __launch_bounds__(256) void k_q(const float* __restrict__ s,
                                           const float* __restrict__ gw1,
                                           const float* __restrict__ gb1,
                                           const float* __restrict__ gw2,
                                           float* __restrict__ q) {
    __shared__ float sg1[H1D], sb1[H1D];
    int tid = threadIdx.x;
    for (int i = tid; i < H1D; i += 256) { sg1[i] = gw1[i]; sb1[i] = gb1[i]; }
    __syncthreads();
    int c = tid & 63;
    int row = blockIdx.x * 4 + (tid >> 6);
    float sv = s[row];
    float a0 = 0.f, a1 = 0.f, a2 = 0.f, a3 = 0.f;
    for (int j = 0; j < H1D; j += 4) {
        float h0 = fmaxf(fmaf(sv, sg1[j + 0], sb1[j + 0]), 0.f);
        float h1 = fmaxf(fmaf(sv, sg1[j + 1], sb1[j + 1]), 0.f);
        float h2 = fmaxf(fmaf(sv, sg1[j + 2], sb1[j + 2]), 0.f);
        float h3 = fmaxf(fmaf(sv, sg1[j + 3], sb1[j + 3]), 0.f);
        a0 = fmaf(h0, gw2[(j + 0) * EMB + c], a0);
        a1 = fmaf(h1, gw2[(j + 1) * EMB + c], a1);
        a2 = fmaf(h2, gw2[(j + 2) * EMB + c], a2);
        a3 = fmaf(h3, gw2[(j + 3) * EMB + c], a3);
    }
    q[row * EMB + c] = (a0 + a1) + (a2 + a3);
}

// ======================= BIG PATH (stateb bf16) =======================

// ---------------- K3a-b: MFMA partial h2 = adj @ q, 64x64 tile, K-split 8 ----------------
#define GCN2_MFMA(BUF)                                                              \
    _Pragma("unroll")                                                               \
    for (int kh = 0; kh < 2; ++kh) {                                                \
        int ch = kh * 4 + fq;                                                       \
        int row = wv * 16 + fr;                                                     \
        bf16x8 aF = *(const bf16x8*)&Asm[BUF][row * 64 + ((ch ^ (row & 7)) << 3)];  \
        bf16x8 bF[4];                                                               \
        _Pragma("unroll")                                                           \
        for (int n = 0; n < 4; ++n) {                                               \
            int col = n * 16 + fr;                                                  \
            bF[n] = *(const bf16x8*)&Bsm[BUF][col * 64 + ((ch ^ (col & 7)) << 3)];  \
        }                                                                           \
        _Pragma("unroll")                                                           \
        for (int n = 0; n < 4; ++n)                                                 \
            acc[n] = __builtin_amdgcn_mfma_f32_16x16x32_bf16(aF, bF[n], acc[n], 0, 0, 0); \
    }

__global__ __launch_bounds__(256) void k_gcn2_mfma_b(const unsigned short* __restrict__ stateb,
                                                     const unsigned short* __restrict__ qbT,
                                                     float* __restrict__ partg) {
    __shared__ __align__(16) unsigned short Asm[2][64 * 64];
    __shared__ __align__(16) unsigned short Bsm[2][64 * 64];
    const int tid = threadIdx.x;
    const int l = tid & 63, wv = tid >> 6;
    const int rbase = blockIdx.x * 64;
    const int kbase0 = blockIdx.y * 1024;   // 16 K-steps of 64

    const unsigned short* aP[2]; const unsigned short* bP[2]; int lb[2];
#pragma unroll
    for (int i = 0; i < 2; ++i) {
        int slot = i * 256 + tid;
        int r = slot >> 3, cg = slot & 7;
        aP[i] = stateb + (size_t)(rbase + r) * NN + kbase0 + ((cg ^ (r & 7)) << 3);
        bP[i] = qbT + (size_t)r * 8192 + kbase0 + ((cg ^ (r & 7)) << 3);
        lb[i] = slot * 8;
    }

    f32x4 acc[4] = {};
    const int fr = l & 15, fq = l >> 4;

#pragma unroll
    for (int i = 0; i < 2; ++i) {
        gload16(aP[i], &Asm[0][lb[i]]);
        gload16(bP[i], &Bsm[0][lb[i]]);
    }

    int buf = 0;
    for (int kt = 0; kt < 15; ++kt) {
#pragma unroll
        for (int i = 0; i < 2; ++i) {
            gload16(aP[i] + (kt + 1) * 64, &Asm[buf ^ 1][lb[i]]);
            gload16(bP[i] + (kt + 1) * 64, &Bsm[buf ^ 1][lb[i]]);
        }
        asm volatile("s_waitcnt vmcnt(4)" ::: "memory");
        __builtin_amdgcn_s_barrier();
        __builtin_amdgcn_sched_barrier(0);
        __builtin_amdgcn_s_setprio(1);
        GCN2_MFMA(buf)
        __builtin_amdgcn_s_setprio(0);
        __builtin_amdgcn_sched_barrier(0);
        __builtin_amdgcn_s_barrier();
        buf ^= 1;
    }
    asm volatile("s_waitcnt vmcnt(0)" ::: "memory");
    __builtin_amdgcn_s_barrier();
    __builtin_amdgcn_sched_barrier(0);
    GCN2_MFMA(buf)

    float* dst = partg + (size_t)blockIdx.y * (NN * EMB);
#pragma unroll
    for (int n = 0; n < 4; ++n) {
        int row0 = rbase + wv * 16 + fq * 4;
        int col = n * 16 + fr;
#pragma unroll
        for (int j = 0; j < 4; ++j)
            dst[(size_t)(row0 + j) * EMB + col] = acc[n][j];
    }
}

// ---------------- K3b-b: combine -> hb (bf16) ----------------
__global__ __launch_bounds__(256) void k_gcn2_combine_b(const float* __restrict__ partg,
                                                        const float* __restrict__ diag,
                                                        const float* __restrict__ q,
                                                        const float* __restrict__ gb2,
                                                        unsigned short* __restrict__ hb) {
    int tid = threadIdx.x;
    int c = tid & 63;
    int row = blockIdx.x * 4 + (tid >> 6);
    int idx = row * EMB + c;
    float v = gb2[c] - diag[row] * q[idx];
#pragma unroll
    for (int p = 0; p < 8; ++p) v += partg[(size_t)p * NN * EMB + idx];
    v = fmaxf(v, 0.f);
    float mx = v;
#pragma unroll
    for (int m = 32; m >= 1; m >>= 1) mx = fmaxf(mx, __shfl_xor(mx, m));
    float e = expf(v - mx);
    float sum = e;
#pragma unroll
    for (int m = 32; m >= 1; m >>= 1) sum += __shfl_xor(sum, m);
    hb[idx] = f2bf(v - mx - logf(sum));
}

// ---------------- K4-b: MFMA head GEMM, BM=256 BN=128, 512 thr / 8 waves,
// K-split 4, counted-vmcnt dbuf (round-11-verified schedule, bigger tile) ----
#define HEAD1_MFMA(BUF)                                                             \
    _Pragma("unroll")                                                               \
    for (int kh = 0; kh < 2; ++kh) {                                                \
        int ch = kh * 4 + fq;                                                       \
        bf16x8 aF[4], bF[4];                                                        \
        _Pragma("unroll")                                                           \
        for (int m = 0; m < 4; ++m) {                                               \
            int row = wm * 64 + m * 16 + fr;                                        \
            aF[m] = *(const bf16x8*)&Asm[BUF][row * 64 + ((ch ^ (row & 7)) << 3)];  \
        }                                                                           \
        _Pragma("unroll")                                                           \
        for (int n = 0; n < 4; ++n) {                                               \
            int nl = wn * 64 + n * 16 + fr;                                         \
            bF[n] = *(const bf16x8*)&Bsm[BUF][nl * 64 + ((ch ^ (nl & 7)) << 3)];    \
        }                                                                           \
        _Pragma("unroll")                                                           \
        for (int m = 0; m < 4; ++m)                                                 \
            _Pragma("unroll")                                                       \
            for (int n = 0; n < 4; ++n)                                             \
                acc[m][n] = __builtin_amdgcn_mfma_f32_16x16x32_bf16(                \
                    aF[m], bF[n], acc[m][n], 0, 0, 0);                              \
    }

__global__ __launch_bounds__(512) void k_head1_mfma_b(
    const unsigned short* __restrict__ stateb, const unsigned short* __restrict__ hb,
    const int* __restrict__ start, const int* __restrict__ end,
    const unsigned short* __restrict__ fw1t, float* __restrict__ parth) {
    __shared__ __align__(16) unsigned short Asm[2][256 * 64];   // 64 KB
    __shared__ __align__(16) unsigned short Bsm[2][128 * 64];   // 32 KB
    __shared__ int ridx[256];
    const int tid = threadIdx.x;
    const int l = tid & 63, wv = tid >> 6;     // 8 waves
    const int rbase = blockIdx.x * 256, cbase = blockIdx.y * 128;
    const int ks = blockIdx.z, side = ks >> 1, half = ks & 1;
    if (tid < 256) ridx[tid] = (side ? end : start)[rbase + tid];
    __syncthreads();

    // A: 256x64 = 2048 chunks -> 4/thread; B: 128x64 = 1024 -> 2/thread. 6 loads/step.
    const unsigned short* aS[4]; const unsigned short* aH[4]; int aLo[4];
#pragma unroll
    for (int i = 0; i < 4; ++i) {
        int slot = i * 512 + tid;
        int r = slot >> 3, cg = slot & 7;
        int swz = (cg ^ (r & 7)) << 3;
        int gi = ridx[r];
        aS[i] = stateb + (size_t)gi * NN + half * 4096 + swz;
        aH[i] = hb + gi * EMB + swz;
        aLo[i] = slot * 8;
    }
    const unsigned short* bP[2]; int bLo[2];
#pragma unroll
    for (int i = 0; i < 2; ++i) {
        int slot = i * 512 + tid;
        int r = slot >> 3, cg = slot & 7;
        int swz = (cg ^ (r & 7)) << 3;
        bP[i] = fw1t + (size_t)(cbase + r) * 16512 + swz;
        bLo[i] = slot * 8;
    }
    const int kB0 = side * 8192 + half * 4096;
    const int kBtail = 16384 + side * 64;
    const int nsteps = 64 + half;

    f32x4 acc[4][4] = {};
    const int wm = wv >> 1, wn = wv & 1;       // 4M x 2N waves, 64x64 each
    const int fr = l & 15, fq = l >> 4;

    // prologue: stage kt=0 into buf 0 (6 loads)
#pragma unroll
    for (int i = 0; i < 4; ++i) gload16(aS[i], &Asm[0][aLo[i]]);
#pragma unroll
    for (int i = 0; i < 2; ++i) gload16(bP[i] + kB0, &Bsm[0][bLo[i]]);

    int buf = 0;
    for (int kt = 0; kt < nsteps - 1; ++kt) {
        int nxt = kt + 1;
        if (nxt < 64) {
#pragma unroll
            for (int i = 0; i < 4; ++i) gload16(aS[i] + nxt * 64, &Asm[buf ^ 1][aLo[i]]);
#pragma unroll
            for (int i = 0; i < 2; ++i) gload16(bP[i] + kB0 + nxt * 64, &Bsm[buf ^ 1][bLo[i]]);
        } else {
#pragma unroll
            for (int i = 0; i < 4; ++i) gload16(aH[i], &Asm[buf ^ 1][aLo[i]]);
#pragma unroll
            for (int i = 0; i < 2; ++i) gload16(bP[i] + kBtail, &Bsm[buf ^ 1][bLo[i]]);
        }
        asm volatile("s_waitcnt vmcnt(6)" ::: "memory");  // kt's 6 landed; nxt's 6 in flight
        __builtin_amdgcn_s_barrier();
        __builtin_amdgcn_sched_barrier(0);
        __builtin_amdgcn_s_setprio(1);
        HEAD1_MFMA(buf)
        __builtin_amdgcn_s_setprio(0);
        __builtin_amdgcn_sched_barrier(0);
        __builtin_amdgcn_s_barrier();
        buf ^= 1;
    }
    asm volatile("s_waitcnt vmcnt(0)" ::: "memory");
    __builtin_amdgcn_s_barrier();
    __builtin_amdgcn_sched_barrier(0);
    HEAD1_MFMA(buf)

    float* dst = parth + (size_t)ks * (NB * H1D);
#pragma unroll
    for (int m = 0; m < 4; ++m) {
        int row0 = rbase + wm * 64 + m * 16 + fq * 4;
#pragma unroll
        for (int n = 0; n < 4; ++n) {
            int col = cbase + wn * 64 + n * 16 + fr;
#pragma unroll
            for (int j = 0; j < 4; ++j)
                dst[(size_t)(row0 + j) * H1D + col] = acc[m][n][j];
        }
    }
}

// ---------------- K4b-b: y1b = bf16(relu(sum of 4 partials + fb1)) ----------------
__global__ void k_head1_fin4(const float* __restrict__ parth, const float* __restrict__ fb1,
                             unsigned short* __restrict__ y1b) {
    int i = blockIdx.x * blockDim.x + threadIdx.x;  // float4 index
    const size_t S = (size_t)NB * H1D;
    float4 a = *(const float4*)&parth[(size_t)i * 4];
    float4 b = *(const float4*)&parth[S + (size_t)i * 4];
    float4 c = *(const float4*)&parth[2 * S + (size_t)i * 4];
    float4 d = *(const float4*)&parth[3 * S + (size_t)i * 4];
    float4 bias = *(const float4*)&fb1[(i * 4) & 511];
    u16x4 o;
    o[0] = f2bf(fmaxf(a.x + b.x + c.x + d.x + bias.x, 0.f));
    o[1] = f2bf(fmaxf(a.y + b.y + c.y + d.y + bias.y, 0.f));
    o[2] = f2bf(fmaxf(a.z + b.z + c.z + d.z + bias.z, 0.f));
    o[3] = f2bf(fmaxf(a.w + b.w + c.w + d.w + bias.w, 0.f));
    *(u16x4*)&y1b[(size_t)i * 4] = o;
}

// ---------------- K5: y2b = bf16(relu(y1b @ fw2 + fb2)), MFMA, K=512 ----------------
__global__ __launch_bounds__(256) void k_ff1(const unsigned short* __restrict__ A,
                                             const unsigned short* __restrict__ Wt,
                                             const float* __restrict__ bias,
                                             unsigned short* __restrict__ out) {
    __shared__ __align__(16) unsigned short Asm[128 * 64];
    __shared__ __align__(16) unsigned short Bsm[128 * 64];
    const int tid = threadIdx.x;
    const int l = tid & 63, wv = tid >> 6;
    const int rbase = blockIdx.x * 128, cbase = blockIdx.y * 128;

    const unsigned short* aP[4]; const unsigned short* bP[4];
    unsigned short* aL[4]; unsigned short* bL[4];
#pragma unroll
    for (int i = 0; i < 4; ++i) {
        int slot = i * 256 + tid;
        int r = slot >> 3, cg = slot & 7;
        int swz = (cg ^ (r & 7)) << 3;
        aP[i] = A + (size_t)(rbase + r) * 512 + swz;
        bP[i] = Wt + (size_t)(cbase + r) * 512 + swz;
        aL[i] = &Asm[slot * 8];
        bL[i] = &Bsm[slot * 8];
    }

    f32x4 acc[4][4] = {};
    const int wm = wv >> 1, wn = wv & 1;
    const int fr = l & 15, fq = l >> 4;

    for (int kt = 0; kt < 8; ++kt) {
#pragma unroll
        for (int i = 0; i < 4; ++i) {
            gload16(aP[i] + kt * 64, aL[i]);
            gload16(bP[i] + kt * 64, bL[i]);
        }
        __syncthreads();
#pragma unroll
        for (int kh = 0; kh < 2; ++kh) {
            int ch = kh * 4 + fq;
            bf16x8 aF[4], bF[4];
#pragma unroll
            for (int m = 0; m < 4; ++m) {
                int row = wm * 64 + m * 16 + fr;
                aF[m] = *(const bf16x8*)&Asm[row * 64 + ((ch ^ (row & 7)) << 3)];
            }
#pragma unroll
            for (int n = 0; n < 4; ++n) {
                int nl = wn * 64 + n * 16 + fr;
                bF[n] = *(const bf16x8*)&Bsm[nl * 64 + ((ch ^ (nl & 7)) << 3)];
            }
#pragma unroll
            for (int m = 0; m < 4; ++m)
#pragma unroll
                for (int n = 0; n < 4; ++n)
                    acc[m][n] = __builtin_amdgcn_mfma_f32_16x16x32_bf16(
                        aF[m], bF[n], acc[m][n], 0, 0, 0);
        }
        __syncthreads();
    }

#pragma unroll
    for (int m = 0; m < 4; ++m) {
        int row0 = rbase + wm * 64 + m * 16 + fq * 4;
#pragma unroll
        for (int n = 0; n < 4; ++n) {
            int col = cbase + wn * 64 + n * 16 + fr;
            float bv = bias[col];
#pragma unroll
            for (int j = 0; j < 4; ++j)
                out[(size_t)(row0 + j) * 256 + col] = f2bf(fmaxf(acc[m][n][j] + bv, 0.f));
        }
    }
}

// ---------------- K6: y3 = relu(y2b @ fw3 + fb3) fp32, MFMA, K=256 ----------------
__global__ __launch_bounds__(256) void k_ff2(const unsigned short* __restrict__ A,
                                             const unsigned short* __restrict__ Wt,
                                             const float* __restrict__ bias,
                                             float* __restrict__ out) {
    __shared__ __align__(16) unsigned short Asm[128 * 64];
    __shared__ __align__(16) unsigned short Bsm[128 * 64];
    const int tid = threadIdx.x;
    const int l = tid & 63, wv = tid >> 6;
    const int rbase = blockIdx.x * 128, cbase = 0;

    const unsigned short* aP[4]; const unsigned short* bP[4];
    unsigned short* aL[4]; unsigned short* bL[4];
#pragma unroll
    for (int i = 0; i < 4; ++i) {
        int slot = i * 256 + tid;
        int r = slot >> 3, cg = slot & 7;
        int swz = (cg ^ (r & 7)) << 3;
        aP[i] = A + (size_t)(rbase + r) * 256 + swz;
        bP[i] = Wt + (size_t)(cbase + r) * 256 + swz;
        aL[i] = &Asm[slot * 8];
        bL[i] = &Bsm[slot * 8];
    }

    f32x4 acc[4][4] = {};
    const int wm = wv >> 1, wn = wv & 1;
    const int fr = l & 15, fq = l >> 4;

    for (int kt = 0; kt < 4; ++kt) {
#pragma unroll
        for (int i = 0; i < 4; ++i) {
            gload16(aP[i] + kt * 64, aL[i]);
            gload16(bP[i] + kt * 64, bL[i]);
        }
        __syncthreads();
#pragma unroll
        for (int kh = 0; kh < 2; ++kh) {
            int ch = kh * 4 + fq;
            bf16x8 aF[4], bF[4];
#pragma unroll
            for (int m = 0; m < 4; ++m) {
                int row = wm * 64 + m * 16 + fr;
                aF[m] = *(const bf16x8*)&Asm[row * 64 + ((ch ^ (row & 7)) << 3)];
            }
#pragma unroll
            for (int n = 0; n < 4; ++n) {
                int nl = wn * 64 + n * 16 + fr;
                bF[n] = *(const bf16x8*)&Bsm[nl * 64 + ((ch ^ (nl & 7)) << 3)];
            }
#pragma unroll
            for (int m = 0; m < 4; ++m)
#pragma unroll
                for (int n = 0; n < 4; ++n)
                    acc[m][n] = __builtin_amdgcn_mfma_f32_16x16x32_bf16(
                        aF[m], bF[n], acc[m][n], 0, 0, 0);
        }
        __syncthreads();
    }

#pragma unroll
    for (int m = 0; m < 4; ++m) {
        int row0 = rbase + wm * 64 + m * 16 + fq * 4;
#pragma unroll
        for (int n = 0; n < 4; ++n) {
            int col = cbase + wn * 64 + n * 16 + fr;
            float bv = bias[col];
#pragma unroll
            for (int j = 0; j < 4; ++j)
                out[(size_t)(row0 + j) * 128 + col] = fmaxf(acc[m][n][j] + bv, 0.f);
        }
    }
}

// ======================= FALLBACK PATH (round-3, known-good) =======================

__global__ __launch_bounds__(256) void k_gcn2_mfma(const float* __restrict__ state,
                                                   const unsigned short* __restrict__ qbT,
                                                   float* __restrict__ partg) {
    __shared__ __align__(16) unsigned short Asm[2][64 * 64];
    __shared__ __align__(16) unsigned short Bsm[2][64 * 64];
    const int tid = threadIdx.x;
    const int l = tid & 63, wv = tid >> 6;
    const int rbase = blockIdx.x * 64;
    const int kbase0 = blockIdx.y * 1024;

    const float* aptr[2]; int awr[2];
#pragma unroll
    for (int i = 0; i < 2; ++i) {
        int slot = i * 256 + tid;
        int r = slot >> 3, cg = slot & 7;
        aptr[i] = state + (size_t)(rbase + r) * NN + kbase0 + cg * 8;
        awr[i] = r * 64 + ((cg ^ (r & 7)) << 3);
    }
    const unsigned short* bptr[2]; int bbase[2];
#pragma unroll
    for (int i = 0; i < 2; ++i) {
        int c = i * 32 + wv * 8 + (l >> 3);
        int cg = l & 7;
        bptr[i] = qbT + (size_t)c * 8192 + kbase0 + ((cg ^ (c & 7)) << 3);
        bbase[i] = i * 2048 + wv * 512;
    }

    f32x4 acc[4] = {};
    const int fr = l & 15, fq = l >> 4;
    float4 va[2][2];

#pragma unroll
    for (int i = 0; i < 2; ++i) {
        va[i][0] = *(const float4*)aptr[i];
        va[i][1] = *(const float4*)(aptr[i] + 4);
    }
#pragma unroll
    for (int i = 0; i < 2; ++i) {
        u16x8 o;
        o[0] = f2bf(va[i][0].x); o[1] = f2bf(va[i][0].y); o[2] = f2bf(va[i][0].z); o[3] = f2bf(va[i][0].w);
        o[4] = f2bf(va[i][1].x); o[5] = f2bf(va[i][1].y); o[6] = f2bf(va[i][1].z); o[7] = f2bf(va[i][1].w);
        *(u16x8*)&Asm[0][awr[i]] = o;
        gload16(bptr[i], &Bsm[0][bbase[i]]);
    }
    __syncthreads();

    int buf = 0;
    for (int kt = 0; kt < 16; ++kt) {
        if (kt < 15) {
#pragma unroll
            for (int i = 0; i < 2; ++i) {
                gload16(bptr[i] + (kt + 1) * 64, &Bsm[buf ^ 1][bbase[i]]);
                va[i][0] = *(const float4*)(aptr[i] + (kt + 1) * 64);
                va[i][1] = *(const float4*)(aptr[i] + (kt + 1) * 64 + 4);
            }
        }
#pragma unroll
        for (int kh = 0; kh < 2; ++kh) {
            int ch = kh * 4 + fq;
            int row = wv * 16 + fr;
            bf16x8 aF = *(const bf16x8*)&Asm[buf][row * 64 + ((ch ^ (row & 7)) << 3)];
            bf16x8 bF[4];
#pragma unroll
            for (int n = 0; n < 4; ++n) {
                int col = n * 16 + fr;
                bF[n] = *(const bf16x8*)&Bsm[buf][col * 64 + ((ch ^ (col & 7)) << 3)];
            }
#pragma unroll
            for (int n = 0; n < 4; ++n)
                acc[n] = __builtin_amdgcn_mfma_f32_16x16x32_bf16(aF, bF[n], acc[n], 0, 0, 0);
        }
        if (kt < 15) {
#pragma unroll
            for (int i = 0; i < 2; ++i) {
                u16x8 o;
                o[0] = f2bf(va[i][0].x); o[1] = f2bf(va[i][0].y); o[2] = f2bf(va[i][0].z); o[3] = f2bf(va[i][0].w);
                o[4] = f2bf(va[i][1].x); o[5] = f2bf(va[i][1].y); o[6] = f2bf(va[i][1].z); o[7] = f2bf(va[i][1].w);
                *(u16x8*)&Asm[buf ^ 1][awr[i]] = o;
            }
        }
        __syncthreads();
        buf ^= 1;
    }

    float* dst = partg + (size_t)blockIdx.y * (NN * EMB);
#pragma unroll
    for (int n = 0; n < 4; ++n) {
        int row0 = rbase + wv * 16 + fq * 4;
        int col = n * 16 + fr;
#pragma unroll
        for (int j = 0; j < 4; ++j)
            dst[(size_t)(row0 + j) * EMB + col] = acc[n][j];
    }
}

__global__ __launch_bounds__(256) void k_gcn2_combine(const float* __restrict__ partg,
                                                      const float* __restrict__ diag,
                                                      const float* __restrict__ q,
                                                      const float* __restrict__ gb2,
                                                      float* __restrict__ h) {
    int tid = threadIdx.x;
    int c = tid & 63;
    int row = blockIdx.x * 4 + (tid >> 6);
    int idx = row * EMB + c;
    float v = gb2[c] - diag[row] * q[idx];
#pragma unroll
    for (int p = 0; p < 8; ++p) v += partg[(size_t)p * NN * EMB + idx];
    v = fmaxf(v, 0.f);
    float mx = v;
#pragma unroll
    for (int m = 32; m >= 1; m >>= 1) mx = fmaxf(mx, __shfl_xor(mx, m));
    float e = expf(v - mx);
    float sum = e;
#pragma unroll
    for (int m = 32; m >= 1; m >>= 1) sum += __shfl_xor(sum, m);
    h[idx] = v - mx - logf(sum);
}

__global__ __launch_bounds__(256) void k_head1_mfma(
    const float* __restrict__ state, const float* __restrict__ h,
    const int* __restrict__ start, const int* __restrict__ end,
    const unsigned short* __restrict__ fw1t, float* __restrict__ part) {
    __shared__ __align__(16) unsigned short Asm[2][64 * 64];
    __shared__ __align__(16) unsigned short Bsm[2][128 * 64];
    __shared__ int ridx[64];
    const int tid = threadIdx.x;
    const int l = tid & 63, wv = tid >> 6;
    const int rbase = blockIdx.x * 64, cbase = blockIdx.y * 128;
    const int ks = blockIdx.z;
    if (tid < 64) ridx[tid] = (ks ? end : start)[rbase + tid];
    __syncthreads();

    const float* aptr[2]; const float* hptr[2]; int awr[2];
#pragma unroll
    for (int i = 0; i < 2; ++i) {
        int slot = i * 256 + tid;
        int r = slot >> 3, cg = slot & 7;
        int gi = ridx[r];
        aptr[i] = state + (size_t)gi * NN + cg * 8;
        hptr[i] = h + gi * EMB + cg * 8;
        awr[i] = r * 64 + ((cg ^ (r & 7)) << 3);
    }
    const unsigned short* bptr[4]; int bbase[4];
#pragma unroll
    for (int i = 0; i < 4; ++i) {
        int n = i * 32 + wv * 8 + (l >> 3);
        int cg = l & 7;
        bptr[i] = fw1t + (size_t)(cbase + n) * 16512 + ((cg ^ (n & 7)) << 3);
        bbase[i] = i * 2048 + wv * 512;
    }

    f32x4 acc[2][4] = {};
    const int wm = wv >> 1, wn = wv & 1;
    const int fr = l & 15, fq = l >> 4;
    float4 va[2][2];

#pragma unroll
    for (int i = 0; i < 2; ++i) {
        va[i][0] = *(const float4*)aptr[i];
        va[i][1] = *(const float4*)(aptr[i] + 4);
    }
#pragma unroll
    for (int i = 0; i < 2; ++i) {
        u16x8 o;
        o[0] = f2bf(va[i][0].x); o[1] = f2bf(va[i][0].y); o[2] = f2bf(va[i][0].z); o[3] = f2bf(va[i][0].w);
        o[4] = f2bf(va[i][1].x); o[5] = f2bf(va[i][1].y); o[6] = f2bf(va[i][1].z); o[7] = f2bf(va[i][1].w);
        *(u16x8*)&Asm[0][awr[i]] = o;
    }
#pragma unroll
    for (int i = 0; i < 4; ++i) gload16(bptr[i] + ks * 8192, &Bsm[0][bbase[i]]);
    __syncthreads();

    int buf = 0;
    for (int kt = 0; kt < 129; ++kt) {
        if (kt < 128) {
            int nxt = kt + 1;
            int kB = (nxt < 128) ? (ks * 8192 + nxt * 64) : (16384 + ks * 64);
#pragma unroll
            for (int i = 0; i < 4; ++i) gload16(bptr[i] + kB, &Bsm[buf ^ 1][bbase[i]]);
#pragma unroll
            for (int i = 0; i < 2; ++i) {
                const float* src = (nxt < 128) ? (aptr[i] + nxt * 64) : hptr[i];
                va[i][0] = *(const float4*)src;
                va[i][1] = *(const float4*)(src + 4);
            }
        }
#pragma unroll
        for (int kh = 0; kh < 2; ++kh) {
            int ch = kh * 4 + fq;
            bf16x8 aF[2], bF[4];
#pragma unroll
            for (int m = 0; m < 2; ++m) {
                int row = wm * 32 + m * 16 + fr;
                aF[m] = *(const bf16x8*)&Asm[buf][row * 64 + ((ch ^ (row & 7)) << 3)];
            }
#pragma unroll
            for (int n = 0; n < 4; ++n) {
                int nl = wn * 64 + n * 16 + fr;
                bF[n] = *(const bf16x8*)&Bsm[buf][nl * 64 + ((ch ^ (nl & 7)) << 3)];
            }
#pragma unroll
            for (int m = 0; m < 2; ++m)
#pragma unroll
                for (int n = 0; n < 4; ++n)
                    acc[m][n] = __builtin_amdgcn_mfma_f32_16x16x32_bf16(
                        aF[m], bF[n], acc[m][n], 0, 0, 0);
        }
        if (kt < 128) {
#pragma unroll
            for (int i = 0; i < 2; ++i) {
                u16x8 o;
                o[0] = f2bf(va[i][0].x); o[1] = f2bf(va[i][0].y); o[2] = f2bf(va[i][0].z); o[3] = f2bf(va[i][0].w);
                o[4] = f2bf(va[i][1].x); o[5] = f2bf(va[i][1].y); o[6] = f2bf(va[i][1].z); o[7] = f2bf(va[i][1].w);
                *(u16x8*)&Asm[buf ^ 1][awr[i]] = o;
            }
        }
        __syncthreads();
        buf ^= 1;
    }

    float* dst = part + (size_t)ks * (NB * H1D);
#pragma unroll
    for (int m = 0; m < 2; ++m) {
        int row0 = rbase + wm * 32 + m * 16 + fq * 4;
#pragma unroll
        for (int n = 0; n < 4; ++n) {
            int col = cbase + wn * 64 + n * 16 + fr;
#pragma unroll
            for (int j = 0; j < 4; ++j)
                dst[(size_t)(row0 + j) * H1D + col] = acc[m][n][j];
        }
    }
}

__global__ void k_head1_fin(const float* __restrict__ part, const float* __restrict__ fb1,
                            float* __restrict__ y1) {
    int i = blockIdx.x * blockDim.x + threadIdx.x;
    float4 a = *(const float4*)&part[(size_t)i * 4];
    float4 b = *(const float4*)&part[(size_t)NB * H1D + (size_t)i * 4];
    float4 bias = *(const float4*)&fb1[(i * 4) & 511];
    float4 o;
    o.x = fmaxf(a.x + b.x + bias.x, 0.f);
    o.y = fmaxf(a.y + b.y + bias.y, 0.f);
    o.z = fmaxf(a.z + b.z + bias.z, 0.f);
    o.w = fmaxf(a.w + b.w + bias.w, 0.f);
    *(float4*)&y1[(size_t)i * 4] = o;
}

// ---- shared 64x64x64 fp32 tile inner product ----
#define GEMM_INNER(AsM, BsM)                                          \
    _Pragma("unroll")                                                 \
    for (int k4 = 0; k4 < 64; k4 += 4) {                              \
        float av[4][4], bv[4][4];                                     \
        _Pragma("unroll")                                             \
        for (int i = 0; i < 4; ++i)                                   \
            *(float4*)av[i] = *(const float4*)&AsM[4 * row_t + i][k4];\
        _Pragma("unroll")                                             \
        for (int t = 0; t < 4; ++t)                                   \
            *(float4*)bv[t] = *(const float4*)&BsM[k4 + t][4 * col_t];\
        _Pragma("unroll")                                             \
        for (int i = 0; i < 4; ++i) {                                 \
            _Pragma("unroll")                                         \
            for (int t = 0; t < 4; ++t) {                             \
                _Pragma("unroll")                                     \
                for (int j = 0; j < 4; ++j)                           \
                    acc[i][j] = fmaf(av[i][t], bv[t][j], acc[i][j]);  \
            }                                                         \
        }                                                             \
    }

// ---------------- K5/K6 (fallback): generic y = relu(A @ W + b) ----------------
__global__ __launch_bounds__(256) void k_gemm_relu(const float* __restrict__ A,
                                                   const float* __restrict__ W,
                                                   const float* __restrict__ bias,
                                                   float* __restrict__ C,
                                                   int M, int N, int K) {
    __shared__ __align__(16) float As[64][68];
    __shared__ __align__(16) float Bs[64][68];
    int tid = threadIdx.x;
    int rbase = blockIdx.x * 64;
    int cbase = blockIdx.y * 64;
    int row_t = tid >> 4, col_t = tid & 15;
    float acc[4][4] = {};
    for (int kt = 0; kt < K / 64; ++kt) {
        int kbase = kt * 64;
#pragma unroll
        for (int l = 0; l < 4; ++l) {
            int lin = l * 256 + tid;
            int r = lin >> 4, k4 = (lin & 15) << 2;
            float4 v = *(const float4*)&A[(size_t)(rbase + r) * K + kbase + k4];
            As[r][k4 + 0] = v.x; As[r][k4 + 1] = v.y; As[r][k4 + 2] = v.z; As[r][k4 + 3] = v.w;
            float4 w = *(const float4*)&W[(size_t)(kbase + r) * N + cbase + k4];
            Bs[r][k4 + 0] = w.x; Bs[r][k4 + 1] = w.y; Bs[r][k4 + 2] = w.z; Bs[r][k4 + 3] = w.w;
        }
        __syncthreads();
        GEMM_INNER(As, Bs)
        __syncthreads();
    }
#pragma unroll
    for (int i = 0; i < 4; ++i) {
        int row = rbase + 4 * row_t + i;
        int col = cbase + 4 * col_t;
        float4 v;
        v.x = fmaxf(acc[i][0] + bias[col + 0], 0.f);
        v.y = fmaxf(acc[i][1] + bias[col + 1], 0.f);
        v.z = fmaxf(acc[i][2] + bias[col + 2], 0.f);
        v.w = fmaxf(acc[i][3] + bias[col + 3], 0.f);
        *(float4*)&C[(size_t)row * N + col] = v;
    }
}

// ---------------- K7: out = relu(y3 @ fw4 + fb4), N=8 ----------------
__global__ void k_head4(const float* __restrict__ y3, const float* __restrict__ fw4,
                        const float* __restrict__ fb4, float* __restrict__ out) {
    int tid = blockIdx.x * blockDim.x + threadIdx.x;
    int b = tid >> 3, j = tid & 7;
    float acc = fb4[j];
    for (int k = 0; k < 128; ++k)
        acc = fmaf(y3[b * 128 + k], fw4[k * 8 + j], acc);
    out[tid] = fmaxf(acc, 0.f);
}

extern "C" void kernel_launch(void* const* d_in, const int* in_sizes, int n_in,
                              void* d_out, int out_size, void* d_ws, size_t ws_size,
                              hipStream_t stream) {
    const float* state = (const float*)d_in[0];
    const int* start   = (const int*)d_in[1];
    const int* end     = (const int*)d_in[2];
    const float* gw1   = (const float*)d_in[3];
    const float* gb1   = (const float*)d_in[4];
    const float* gw2   = (const float*)d_in[5];
    const float* gb2   = (const float*)d_in[6];
    const float* fw1   = (const float*)d_in[7];
    const float* fb1   = (const float*)d_in[8];
    const float* fw2   = (const float*)d_in[9];
    const float* fb2   = (const float*)d_in[10];
    const float* fw3   = (const float*)d_in[11];
    const float* fb3   = (const float*)d_in[12];
    const float* fw4   = (const float*)d_in[13];
    const float* fb4   = (const float*)d_in[14];
    float* out = (float*)d_out;
    float* ws = (float*)d_ws;

    // ---- BIG path layout (floats). Peak 53,084,160 f = 212.3 MB (ws ~1 GB per fill counter). ----
    const size_t NEED_BIG = 53084160ull * 4ull;
    const size_t NEED_FB  = 9748480ull * 4ull;

    if (ws_size >= NEED_BIG) {
        float* diag = ws;
        float* s    = ws + 8192;
        float* q    = ws + 16384;
        unsigned short* qbT = (unsigned short*)(ws + 540672);
        unsigned short* hb  = (unsigned short*)(ws + 802816);
        float* partg = ws + 1064960;
        unsigned short* fw1t = (unsigned short*)(ws + 5259264);
        unsigned short* stateb = (unsigned short*)(ws + 9486336);
        float* parth = ws + 43040768;
        unsigned short* fw2t = (unsigned short*)(ws + 51429376);
        unsigned short* fw3t = (unsigned short*)(ws + 51494912);
        unsigned short* y1b  = (unsigned short*)(ws + 51511296);
        unsigned short* y2b  = (unsigned short*)(ws + 52559872);
        float* y3   = ws + 7356416;

        k_diag<<<32, 256, 0, stream>>>(state, diag);
        k_convert<<<8192, 256, 0, stream>>>(state, diag, stateb, s);
        k_tr_fw1<<<dim3(258, 8), 256, 0, stream>>>(fw1, fw1t);
        k_tr_w<<<dim3(8, 4), 256, 0, stream>>>(fw2, fw2t, 512, 256);
        k_tr_w<<<dim3(4, 2), 256, 0, stream>>>(fw3, fw3t, 256, 128);
        k_q<<<2048, 256, 0, stream>>>(s, gw1, gb1, gw2, q);
        k_tr_q<<<128, 256, 0, stream>>>(q, qbT);
        k_gcn2_mfma_b<<<dim3(128, 8), 256, 0, stream>>>(stateb, qbT, partg);
        k_gcn2_combine_b<<<2048, 256, 0, stream>>>(partg, diag, q, gb2, hb);
        k_head1_mfma_b<<<dim3(16, 4, 4), 512, 0, stream>>>(stateb, hb, start, end, fw1t, parth);
        k_head1_fin4<<<2048, 256, 0, stream>>>(parth, fb1, y1b);
        k_ff1<<<dim3(32, 2), 256, 0, stream>>>(y1b, fw2t, fb2, y2b);
        k_ff2<<<dim3(32, 1), 256, 0, stream>>>(y2b, fw3t, fb3, y3);
        k_head4<<<128, 256, 0, stream>>>(y3, fw4, fb4, out);
        return;
    }

    // ---- FALLBACK: round-3 layout (39 MB) ----
    if (ws_size < NEED_FB) return;

    float* diag = ws;
    float* s    = ws + 8192;
    float* q    = ws + 16384;
    unsigned short* qbT = (unsigned short*)(ws + 540672);
    float* h    = ws + 802816;
    float* partg = ws + 1327104;
    unsigned short* fw1t = (unsigned short*)(ws + 5521408);
    float* parth = ws + 1327104;
    float* y1   = ws + 5521408;
    float* y2   = ws + 16384;
    float* y3   = ws + 7618560;

    k_diag<<<32, 256, 0, stream>>>(state, diag);
    k_tr_fw1<<<dim3(258, 8), 256, 0, stream>>>(fw1, fw1t);
    k_rowdot<<<8192, 256, 0, stream>>>(state, diag, s);
    k_q<<<2048, 256, 0, stream>>>(s, gw1, gb1, gw2, q);
    k_tr_q<<<128, 256, 0, stream>>>(q, qbT);
    k_gcn2_mfma<<<dim3(128, 8), 256, 0, stream>>>(state, qbT, partg);
    k_gcn2_combine<<<2048, 256, 0, stream>>>(partg, diag, q, gb2, h);
    k_head1_mfma<<<dim3(64, 4, 2), 256, 0, stream>>>(state, h, start, end, fw1t, parth);
    k_head1_fin<<<2048, 256, 0, stream>>>(parth, fb1, y1);
    k_gemm_relu<<<dim3(64, 4), 256, 0, stream>>>(y1, fw2, fb2, y2, NB, 256, 512);
    k_gemm_relu<<<dim3(64, 2), 256, 0, stream>>>(y2, fw3, fb3, y3, NB, 128, 256);
    k_head4<<<128, 256, 0, stream>>>(y3, fw4, fb4, out);
}

// Round 13
// 275.850 us; speedup vs baseline: 1.0579x; 1.0579x over previous
//
#include <hip/hip_runtime.h>
#include <hip/hip_bf16.h>
#include <math.h>

#define NN 8192
#define EMB 64
#define H1D 512
#define NB 4096

typedef __bf16 bf16x8 __attribute__((ext_vector_type(8)));
typedef float f32x4 __attribute__((ext_vector_type(4)));
typedef unsigned short u16x8 __attribute__((ext_vector_type(8)));
typedef unsigned short u16x4 __attribute__((ext_vector_type(4)));

__device__ __forceinline__ unsigned short f2bf(float f) {
    return __bfloat16_as_ushort(__float2bfloat16(f));
}

__device__ __forceinline__ void gload16(const void* g, void* l) {
    __builtin_amdgcn_global_load_lds(
        (const __attribute__((address_space(1))) void*)g,
        (__attribute__((address_space(3))) void*)l, 16, 0, 0);
}

// ---------------- K0: extract diagonal ----------------
__global__ void k_diag(const float* __restrict__ state, float* __restrict__ diag) {
    int i = blockIdx.x * blockDim.x + threadIdx.x;
    if (i < NN) diag[i] = state[(size_t)i * NN + i];
}

// ---------------- fused: state fp32 -> stateb bf16, + rowdot s[i] ----------------
__global__ __launch_bounds__(256) void k_convert(const float* __restrict__ state,
                                                 const float* __restrict__ diag,
                                                 unsigned short* __restrict__ stateb,
                                                 float* __restrict__ s) {
    int row = blockIdx.x;
    int tid = threadIdx.x;
    const float4* st4 = (const float4*)(state + (size_t)row * NN);
    const float4* dg4 = (const float4*)diag;
    unsigned short* drow = stateb + (size_t)row * NN;
    float acc = 0.f;
#pragma unroll
    for (int t = 0; t < 8; ++t) {
        int f = t * 256 + tid;
        float4 a = st4[f], d = dg4[f];
        acc += a.x * d.x + a.y * d.y + a.z * d.z + a.w * d.w;
        u16x4 o;
        o[0] = f2bf(a.x); o[1] = f2bf(a.y); o[2] = f2bf(a.z); o[3] = f2bf(a.w);
        *(u16x4*)&drow[f * 4] = o;
    }
#pragma unroll
    for (int m = 32; m >= 1; m >>= 1) acc += __shfl_xor(acc, m);
    __shared__ float red[4];
    if ((tid & 63) == 0) red[tid >> 6] = acc;
    __syncthreads();
    if (tid == 0) {
        float tot = red[0] + red[1] + red[2] + red[3];
        float d = diag[row];
        s[row] = tot - d * d;
    }
}

// ---------------- fw1 [16512][512] -> fw1t bf16 [512][16512] ----------------
__global__ __launch_bounds__(256) void k_tr_fw1(const float* __restrict__ fw1,
                                                unsigned short* __restrict__ fw1t) {
    __shared__ float t[64][65];
    int kb = blockIdx.x * 64, nb = blockIdx.y * 64;
    int tid = threadIdx.x;
#pragma unroll
    for (int i = 0; i < 4; ++i) {
        int lin = i * 256 + tid;
        int r = lin >> 4, c4 = (lin & 15) << 2;
        float4 v = *(const float4*)&fw1[(size_t)(kb + r) * 512 + nb + c4];
        t[r][c4] = v.x; t[r][c4 + 1] = v.y; t[r][c4 + 2] = v.z; t[r][c4 + 3] = v.w;
    }
    __syncthreads();
#pragma unroll
    for (int i = 0; i < 4; ++i) {
        int lin = i * 256 + tid;
        int n = lin >> 4, k4 = (lin & 15) << 2;
        u16x4 o;
        o[0] = f2bf(t[k4 + 0][n]); o[1] = f2bf(t[k4 + 1][n]);
        o[2] = f2bf(t[k4 + 2][n]); o[3] = f2bf(t[k4 + 3][n]);
        *(u16x4*)&fw1t[(size_t)(nb + n) * 16512 + kb + k4] = o;
    }
}

// ---------------- generic W [K][N] fp32 -> Wt bf16 [N][K] (dims % 64 == 0) ----------------
__global__ __launch_bounds__(256) void k_tr_w(const float* __restrict__ W,
                                              unsigned short* __restrict__ Wt,
                                              int K, int N) {
    __shared__ float t[64][65];
    int kb = blockIdx.x * 64, nb = blockIdx.y * 64;
    int tid = threadIdx.x;
#pragma unroll
    for (int i = 0; i < 4; ++i) {
        int lin = i * 256 + tid;
        int r = lin >> 4, c4 = (lin & 15) << 2;
        float4 v = *(const float4*)&W[(size_t)(kb + r) * N + nb + c4];
        t[r][c4] = v.x; t[r][c4 + 1] = v.y; t[r][c4 + 2] = v.z; t[r][c4 + 3] = v.w;
    }
    __syncthreads();
#pragma unroll
    for (int i = 0; i < 4; ++i) {
        int lin = i * 256 + tid;
        int n = lin >> 4, k4 = (lin & 15) << 2;
        u16x4 o;
        o[0] = f2bf(t[k4 + 0][n]); o[1] = f2bf(t[k4 + 1][n]);
        o[2] = f2bf(t[k4 + 2][n]); o[3] = f2bf(t[k4 + 3][n]);
        *(u16x4*)&Wt[(size_t)(nb + n) * K + kb + k4] = o;
    }
}

// ---------------- q [8192][64] fp32 -> qbT bf16 [64][8192] ----------------
__global__ __launch_bounds__(256) void k_tr_q(const float* __restrict__ q,
                                              unsigned short* __restrict__ qbT) {
    __shared__ float t[64][65];
    int kb = blockIdx.x * 64;
    int tid = threadIdx.x;
#pragma unroll
    for (int i = 0; i < 4; ++i) {
        int lin = i * 256 + tid;
        int r = lin >> 4, c4 = (lin & 15) << 2;
        float4 v = *(const float4*)&q[(size_t)(kb + r) * 64 + c4];
        t[r][c4] = v.x; t[r][c4 + 1] = v.y; t[r][c4 + 2] = v.z; t[r][c4 + 3] = v.w;
    }
    __syncthreads();
#pragma unroll
    for (int i = 0; i < 4; ++i) {
        int lin = i * 256 + tid;
        int c = lin >> 4, k4 = (lin & 15) << 2;
        u16x4 o;
        o[0] = f2bf(t[k4 + 0][c]); o[1] = f2bf(t[k4 + 1][c]);
        o[2] = f2bf(t[k4 + 2][c]); o[3] = f2bf(t[k4 + 3][c]);
        *(u16x4*)&qbT[(size_t)c * 8192 + kb + k4] = o;
    }
}

// ---------------- K1 (fallback): s[i] = sum_k adj[i,k]*diag[k] ----------------
__global__ __launch_bounds__(256) void k_rowdot(const float* __restrict__ state,
                                                const float* __restrict__ diag,
                                                float* __restrict__ s) {
    int row = blockIdx.x;
    int tid = threadIdx.x;
    const float4* st4 = (const float4*)(state + (size_t)row * NN);
    const float4* dg4 = (const float4*)diag;
    float acc = 0.f;
#pragma unroll
    for (int t = 0; t < 8; ++t) {
        int f = t * 256 + tid;
        float4 a = st4[f], d = dg4[f];
        acc += a.x * d.x + a.y * d.y + a.z * d.z + a.w * d.w;
    }
#pragma unroll
    for (int m = 32; m >= 1; m >>= 1) acc += __shfl_xor(acc, m);
    __shared__ float red[4];
    if ((tid & 63) == 0) red[tid >> 6] = acc;
    __syncthreads();
    if (tid == 0) {
        float tot = red[0] + red[1] + red[2] + red[3];
        float d = diag[row];
        s[row] = tot - d * d;
    }
}

// ---------------- K2: q[k][c] = sum_j relu(s[k]*gw1[j]+gb1[j]) * gw2[j][c] ----------------
__global__ __launch_bounds__(256) void k_q(const float* __restrict__ s,
                                           const float* __restrict__ gw1,
                                           const float* __restrict__ gb1,
                                           const float* __restrict__ gw2,
                                           float* __restrict__ q) {
    __shared__ float sg1[H1D], sb1[H1D];
    int tid = threadIdx.x;
    for (int i = tid; i < H1D; i += 256) { sg1[i] = gw1[i]; sb1[i] = gb1[i]; }
    __syncthreads();
    int c = tid & 63;
    int row = blockIdx.x * 4 + (tid >> 6);
    float sv = s[row];
    float a0 = 0.f, a1 = 0.f, a2 = 0.f, a3 = 0.f;
    for (int j = 0; j < H1D; j += 4) {
        float h0 = fmaxf(fmaf(sv, sg1[j + 0], sb1[j + 0]), 0.f);
        float h1 = fmaxf(fmaf(sv, sg1[j + 1], sb1[j + 1]), 0.f);
        float h2 = fmaxf(fmaf(sv, sg1[j + 2], sb1[j + 2]), 0.f);
        float h3 = fmaxf(fmaf(sv, sg1[j + 3], sb1[j + 3]), 0.f);
        a0 = fmaf(h0, gw2[(j + 0) * EMB + c], a0);
        a1 = fmaf(h1, gw2[(j + 1) * EMB + c], a1);
        a2 = fmaf(h2, gw2[(j + 2) * EMB + c], a2);
        a3 = fmaf(h3, gw2[(j + 3) * EMB + c], a3);
    }
    q[row * EMB + c] = (a0 + a1) + (a2 + a3);
}

// ======================= BIG PATH (stateb bf16) =======================

// ---------------- K3a-b: MFMA partial h2 = adj @ q, 64x64 tile, K-split 8 ----------------
#define GCN2_MFMA(BUF)                                                              \
    _Pragma("unroll")                                                               \
    for (int kh = 0; kh < 2; ++kh) {                                                \
        int ch = kh * 4 + fq;                                                       \
        int row = wv * 16 + fr;                                                     \
        bf16x8 aF = *(const bf16x8*)&Asm[BUF][row * 64 + ((ch ^ (row & 7)) << 3)];  \
        bf16x8 bF[4];                                                               \
        _Pragma("unroll")                                                           \
        for (int n = 0; n < 4; ++n) {                                               \
            int col = n * 16 + fr;                                                  \
            bF[n] = *(const bf16x8*)&Bsm[BUF][col * 64 + ((ch ^ (col & 7)) << 3)];  \
        }                                                                           \
        _Pragma("unroll")                                                           \
        for (int n = 0; n < 4; ++n)                                                 \
            acc[n] = __builtin_amdgcn_mfma_f32_16x16x32_bf16(aF, bF[n], acc[n], 0, 0, 0); \
    }

__global__ __launch_bounds__(256) void k_gcn2_mfma_b(const unsigned short* __restrict__ stateb,
                                                     const unsigned short* __restrict__ qbT,
                                                     float* __restrict__ partg) {
    __shared__ __align__(16) unsigned short Asm[2][64 * 64];
    __shared__ __align__(16) unsigned short Bsm[2][64 * 64];
    const int tid = threadIdx.x;
    const int l = tid & 63, wv = tid >> 6;
    const int rbase = blockIdx.x * 64;
    const int kbase0 = blockIdx.y * 1024;   // 16 K-steps of 64

    const unsigned short* aP[2]; const unsigned short* bP[2]; int lb[2];
#pragma unroll
    for (int i = 0; i < 2; ++i) {
        int slot = i * 256 + tid;
        int r = slot >> 3, cg = slot & 7;
        aP[i] = stateb + (size_t)(rbase + r) * NN + kbase0 + ((cg ^ (r & 7)) << 3);
        bP[i] = qbT + (size_t)r * 8192 + kbase0 + ((cg ^ (r & 7)) << 3);
        lb[i] = slot * 8;
    }

    f32x4 acc[4] = {};
    const int fr = l & 15, fq = l >> 4;

#pragma unroll
    for (int i = 0; i < 2; ++i) {
        gload16(aP[i], &Asm[0][lb[i]]);
        gload16(bP[i], &Bsm[0][lb[i]]);
    }

    int buf = 0;
    for (int kt = 0; kt < 15; ++kt) {
#pragma unroll
        for (int i = 0; i < 2; ++i) {
            gload16(aP[i] + (kt + 1) * 64, &Asm[buf ^ 1][lb[i]]);
            gload16(bP[i] + (kt + 1) * 64, &Bsm[buf ^ 1][lb[i]]);
        }
        asm volatile("s_waitcnt vmcnt(4)" ::: "memory");
        __builtin_amdgcn_s_barrier();
        __builtin_amdgcn_sched_barrier(0);
        __builtin_amdgcn_s_setprio(1);
        GCN2_MFMA(buf)
        __builtin_amdgcn_s_setprio(0);
        __builtin_amdgcn_sched_barrier(0);
        __builtin_amdgcn_s_barrier();
        buf ^= 1;
    }
    asm volatile("s_waitcnt vmcnt(0)" ::: "memory");
    __builtin_amdgcn_s_barrier();
    __builtin_amdgcn_sched_barrier(0);
    GCN2_MFMA(buf)

    float* dst = partg + (size_t)blockIdx.y * (NN * EMB);
#pragma unroll
    for (int n = 0; n < 4; ++n) {
        int row0 = rbase + wv * 16 + fq * 4;
        int col = n * 16 + fr;
#pragma unroll
        for (int j = 0; j < 4; ++j)
            dst[(size_t)(row0 + j) * EMB + col] = acc[n][j];
    }
}

// ---------------- K3b-b: combine -> hb (bf16) ----------------
__global__ __launch_bounds__(256) void k_gcn2_combine_b(const float* __restrict__ partg,
                                                        const float* __restrict__ diag,
                                                        const float* __restrict__ q,
                                                        const float* __restrict__ gb2,
                                                        unsigned short* __restrict__ hb) {
    int tid = threadIdx.x;
    int c = tid & 63;
    int row = blockIdx.x * 4 + (tid >> 6);
    int idx = row * EMB + c;
    float v = gb2[c] - diag[row] * q[idx];
#pragma unroll
    for (int p = 0; p < 8; ++p) v += partg[(size_t)p * NN * EMB + idx];
    v = fmaxf(v, 0.f);
    float mx = v;
#pragma unroll
    for (int m = 32; m >= 1; m >>= 1) mx = fmaxf(mx, __shfl_xor(mx, m));
    float e = expf(v - mx);
    float sum = e;
#pragma unroll
    for (int m = 32; m >= 1; m >>= 1) sum += __shfl_xor(sum, m);
    hb[idx] = f2bf(v - mx - logf(sum));
}

// ---------------- K4-b: MFMA head GEMM, 128x128, K-split 4, counted-vmcnt dbuf ----
#define HEAD1_MFMA(BUF)                                                             \
    _Pragma("unroll")                                                               \
    for (int kh = 0; kh < 2; ++kh) {                                                \
        int ch = kh * 4 + fq;                                                       \
        bf16x8 aF[4], bF[4];                                                        \
        _Pragma("unroll")                                                           \
        for (int m = 0; m < 4; ++m) {                                               \
            int row = wm * 64 + m * 16 + fr;                                        \
            aF[m] = *(const bf16x8*)&Asm[BUF][row * 64 + ((ch ^ (row & 7)) << 3)];  \
        }                                                                           \
        _Pragma("unroll")                                                           \
        for (int n = 0; n < 4; ++n) {                                               \
            int nl = wn * 64 + n * 16 + fr;                                         \
            bF[n] = *(const bf16x8*)&Bsm[BUF][nl * 64 + ((ch ^ (nl & 7)) << 3)];    \
        }                                                                           \
        _Pragma("unroll")                                                           \
        for (int m = 0; m < 4; ++m)                                                 \
            _Pragma("unroll")                                                       \
            for (int n = 0; n < 4; ++n)                                             \
                acc[m][n] = __builtin_amdgcn_mfma_f32_16x16x32_bf16(                \
                    aF[m], bF[n], acc[m][n], 0, 0, 0);                              \
    }

__global__ __launch_bounds__(256) void k_head1_mfma_b(
    const unsigned short* __restrict__ stateb, const unsigned short* __restrict__ hb,
    const int* __restrict__ start, const int* __restrict__ end,
    const unsigned short* __restrict__ fw1t, float* __restrict__ parth) {
    __shared__ __align__(16) unsigned short Asm[2][128 * 64];
    __shared__ __align__(16) unsigned short Bsm[2][128 * 64];
    __shared__ int ridx[128];
    const int tid = threadIdx.x;
    const int l = tid & 63, wv = tid >> 6;
    const int rbase = blockIdx.x * 128, cbase = blockIdx.y * 128;
    const int ks = blockIdx.z, side = ks >> 1, half = ks & 1;
    if (tid < 128) ridx[tid] = (side ? end : start)[rbase + tid];
    __syncthreads();

    const unsigned short* aS[4]; const unsigned short* aH[4];
    const unsigned short* bP[4];
    int aLo[4], bLo[4];
#pragma unroll
    for (int i = 0; i < 4; ++i) {
        int slot = i * 256 + tid;
        int r = slot >> 3, cg = slot & 7;
        int swz = (cg ^ (r & 7)) << 3;
        int gi = ridx[r];
        aS[i] = stateb + (size_t)gi * NN + half * 4096 + swz;
        aH[i] = hb + gi * EMB + swz;
        bP[i] = fw1t + (size_t)(cbase + r) * 16512 + swz;
        aLo[i] = slot * 8;
        bLo[i] = slot * 8;
    }
    const int kB0 = side * 8192 + half * 4096;
    const int kBtail = 16384 + side * 64;
    const int nsteps = 64 + half;

    f32x4 acc[4][4] = {};
    const int wm = wv >> 1, wn = wv & 1;
    const int fr = l & 15, fq = l >> 4;

    // prologue: stage kt=0 into buf 0 (8 loads)
#pragma unroll
    for (int i = 0; i < 4; ++i) {
        gload16(aS[i], &Asm[0][aLo[i]]);
        gload16(bP[i] + kB0, &Bsm[0][bLo[i]]);
    }

    int buf = 0;
    for (int kt = 0; kt < nsteps - 1; ++kt) {
        int nxt = kt + 1;
        if (nxt < 64) {
#pragma unroll
            for (int i = 0; i < 4; ++i) {
                gload16(aS[i] + nxt * 64, &Asm[buf ^ 1][aLo[i]]);
                gload16(bP[i] + kB0 + nxt * 64, &Bsm[buf ^ 1][bLo[i]]);
            }
        } else {
#pragma unroll
            for (int i = 0; i < 4; ++i) {
                gload16(aH[i], &Asm[buf ^ 1][aLo[i]]);
                gload16(bP[i] + kBtail, &Bsm[buf ^ 1][bLo[i]]);
            }
        }
        asm volatile("s_waitcnt vmcnt(8)" ::: "memory");  // kt's 8 landed; nxt's 8 in flight
        __builtin_amdgcn_s_barrier();
        __builtin_amdgcn_sched_barrier(0);
        __builtin_amdgcn_s_setprio(1);
        HEAD1_MFMA(buf)
        __builtin_amdgcn_s_setprio(0);
        __builtin_amdgcn_sched_barrier(0);
        __builtin_amdgcn_s_barrier();
        buf ^= 1;
    }
    asm volatile("s_waitcnt vmcnt(0)" ::: "memory");
    __builtin_amdgcn_s_barrier();
    __builtin_amdgcn_sched_barrier(0);
    HEAD1_MFMA(buf)

    float* dst = parth + (size_t)ks * (NB * H1D);
#pragma unroll
    for (int m = 0; m < 4; ++m) {
        int row0 = rbase + wm * 64 + m * 16 + fq * 4;
#pragma unroll
        for (int n = 0; n < 4; ++n) {
            int col = cbase + wn * 64 + n * 16 + fr;
#pragma unroll
            for (int j = 0; j < 4; ++j)
                dst[(size_t)(row0 + j) * H1D + col] = acc[m][n][j];
        }
    }
}

// ---------------- K4b-b: y1b = bf16(relu(sum of 4 partials + fb1)) ----------------
__global__ void k_head1_fin4(const float* __restrict__ parth, const float* __restrict__ fb1,
                             unsigned short* __restrict__ y1b) {
    int i = blockIdx.x * blockDim.x + threadIdx.x;  // float4 index
    const size_t S = (size_t)NB * H1D;
    float4 a = *(const float4*)&parth[(size_t)i * 4];
    float4 b = *(const float4*)&parth[S + (size_t)i * 4];
    float4 c = *(const float4*)&parth[2 * S + (size_t)i * 4];
    float4 d = *(const float4*)&parth[3 * S + (size_t)i * 4];
    float4 bias = *(const float4*)&fb1[(i * 4) & 511];
    u16x4 o;
    o[0] = f2bf(fmaxf(a.x + b.x + c.x + d.x + bias.x, 0.f));
    o[1] = f2bf(fmaxf(a.y + b.y + c.y + d.y + bias.y, 0.f));
    o[2] = f2bf(fmaxf(a.z + b.z + c.z + d.z + bias.z, 0.f));
    o[3] = f2bf(fmaxf(a.w + b.w + c.w + d.w + bias.w, 0.f));
    *(u16x4*)&y1b[(size_t)i * 4] = o;
}

// ---------------- K5: y2b = bf16(relu(y1b @ fw2 + fb2)), MFMA, K=512 ----------------
__global__ __launch_bounds__(256) void k_ff1(const unsigned short* __restrict__ A,
                                             const unsigned short* __restrict__ Wt,
                                             const float* __restrict__ bias,
                                             unsigned short* __restrict__ out) {
    __shared__ __align__(16) unsigned short Asm[128 * 64];
    __shared__ __align__(16) unsigned short Bsm[128 * 64];
    const int tid = threadIdx.x;
    const int l = tid & 63, wv = tid >> 6;
    const int rbase = blockIdx.x * 128, cbase = blockIdx.y * 128;

    const unsigned short* aP[4]; const unsigned short* bP[4];
    unsigned short* aL[4]; unsigned short* bL[4];
#pragma unroll
    for (int i = 0; i < 4; ++i) {
        int slot = i * 256 + tid;
        int r = slot >> 3, cg = slot & 7;
        int swz = (cg ^ (r & 7)) << 3;
        aP[i] = A + (size_t)(rbase + r) * 512 + swz;
        bP[i] = Wt + (size_t)(cbase + r) * 512 + swz;
        aL[i] = &Asm[slot * 8];
        bL[i] = &Bsm[slot * 8];
    }

    f32x4 acc[4][4] = {};
    const int wm = wv >> 1, wn = wv & 1;
    const int fr = l & 15, fq = l >> 4;

    for (int kt = 0; kt < 8; ++kt) {
#pragma unroll
        for (int i = 0; i < 4; ++i) {
            gload16(aP[i] + kt * 64, aL[i]);
            gload16(bP[i] + kt * 64, bL[i]);
        }
        __syncthreads();
#pragma unroll
        for (int kh = 0; kh < 2; ++kh) {
            int ch = kh * 4 + fq;
            bf16x8 aF[4], bF[4];
#pragma unroll
            for (int m = 0; m < 4; ++m) {
                int row = wm * 64 + m * 16 + fr;
                aF[m] = *(const bf16x8*)&Asm[row * 64 + ((ch ^ (row & 7)) << 3)];
            }
#pragma unroll
            for (int n = 0; n < 4; ++n) {
                int nl = wn * 64 + n * 16 + fr;
                bF[n] = *(const bf16x8*)&Bsm[nl * 64 + ((ch ^ (nl & 7)) << 3)];
            }
#pragma unroll
            for (int m = 0; m < 4; ++m)
#pragma unroll
                for (int n = 0; n < 4; ++n)
                    acc[m][n] = __builtin_amdgcn_mfma_f32_16x16x32_bf16(
                        aF[m], bF[n], acc[m][n], 0, 0, 0);
        }
        __syncthreads();
    }

#pragma unroll
    for (int m = 0; m < 4; ++m) {
        int row0 = rbase + wm * 64 + m * 16 + fq * 4;
#pragma unroll
        for (int n = 0; n < 4; ++n) {
            int col = cbase + wn * 64 + n * 16 + fr;
            float bv = bias[col];
#pragma unroll
            for (int j = 0; j < 4; ++j)
                out[(size_t)(row0 + j) * 256 + col] = f2bf(fmaxf(acc[m][n][j] + bv, 0.f));
        }
    }
}

// ---------------- K6: y3 = relu(y2b @ fw3 + fb3) fp32, MFMA, K=256 ----------------
__global__ __launch_bounds__(256) void k_ff2(const unsigned short* __restrict__ A,
                                             const unsigned short* __restrict__ Wt,
                                             const float* __restrict__ bias,
                                             float* __restrict__ out) {
    __shared__ __align__(16) unsigned short Asm[128 * 64];
    __shared__ __align__(16) unsigned short Bsm[128 * 64];
    const int tid = threadIdx.x;
    const int l = tid & 63, wv = tid >> 6;
    const int rbase = blockIdx.x * 128, cbase = 0;

    const unsigned short* aP[4]; const unsigned short* bP[4];
    unsigned short* aL[4]; unsigned short* bL[4];
#pragma unroll
    for (int i = 0; i < 4; ++i) {
        int slot = i * 256 + tid;
        int r = slot >> 3, cg = slot & 7;
        int swz = (cg ^ (r & 7)) << 3;
        aP[i] = A + (size_t)(rbase + r) * 256 + swz;
        bP[i] = Wt + (size_t)(cbase + r) * 256 + swz;
        aL[i] = &Asm[slot * 8];
        bL[i] = &Bsm[slot * 8];
    }

    f32x4 acc[4][4] = {};
    const int wm = wv >> 1, wn = wv & 1;
    const int fr = l & 15, fq = l >> 4;

    for (int kt = 0; kt < 4; ++kt) {
#pragma unroll
        for (int i = 0; i < 4; ++i) {
            gload16(aP[i] + kt * 64, aL[i]);
            gload16(bP[i] + kt * 64, bL[i]);
        }
        __syncthreads();
#pragma unroll
        for (int kh = 0; kh < 2; ++kh) {
            int ch = kh * 4 + fq;
            bf16x8 aF[4], bF[4];
#pragma unroll
            for (int m = 0; m < 4; ++m) {
                int row = wm * 64 + m * 16 + fr;
                aF[m] = *(const bf16x8*)&Asm[row * 64 + ((ch ^ (row & 7)) << 3)];
            }
#pragma unroll
            for (int n = 0; n < 4; ++n) {
                int nl = wn * 64 + n * 16 + fr;
                bF[n] = *(const bf16x8*)&Bsm[nl * 64 + ((ch ^ (nl & 7)) << 3)];
            }
#pragma unroll
            for (int m = 0; m < 4; ++m)
#pragma unroll
                for (int n = 0; n < 4; ++n)
                    acc[m][n] = __builtin_amdgcn_mfma_f32_16x16x32_bf16(
                        aF[m], bF[n], acc[m][n], 0, 0, 0);
        }
        __syncthreads();
    }

#pragma unroll
    for (int m = 0; m < 4; ++m) {
        int row0 = rbase + wm * 64 + m * 16 + fq * 4;
#pragma unroll
        for (int n = 0; n < 4; ++n) {
            int col = cbase + wn * 64 + n * 16 + fr;
            float bv = bias[col];
#pragma unroll
            for (int j = 0; j < 4; ++j)
                out[(size_t)(row0 + j) * 128 + col] = fmaxf(acc[m][n][j] + bv, 0.f);
        }
    }
}

// ======================= FALLBACK PATH (round-3, known-good) =======================

__global__ __launch_bounds__(256) void k_gcn2_mfma(const float* __restrict__ state,
                                                   const unsigned short* __restrict__ qbT,
                                                   float* __restrict__ partg) {
    __shared__ __align__(16) unsigned short Asm[2][64 * 64];
    __shared__ __align__(16) unsigned short Bsm[2][64 * 64];
    const int tid = threadIdx.x;
    const int l = tid & 63, wv = tid >> 6;
    const int rbase = blockIdx.x * 64;
    const int kbase0 = blockIdx.y * 1024;

    const float* aptr[2]; int awr[2];
#pragma unroll
    for (int i = 0; i < 2; ++i) {
        int slot = i * 256 + tid;
        int r = slot >> 3, cg = slot & 7;
        aptr[i] = state + (size_t)(rbase + r) * NN + kbase0 + cg * 8;
        awr[i] = r * 64 + ((cg ^ (r & 7)) << 3);
    }
    const unsigned short* bptr[2]; int bbase[2];
#pragma unroll
    for (int i = 0; i < 2; ++i) {
        int c = i * 32 + wv * 8 + (l >> 3);
        int cg = l & 7;
        bptr[i] = qbT + (size_t)c * 8192 + kbase0 + ((cg ^ (c & 7)) << 3);
        bbase[i] = i * 2048 + wv * 512;
    }

    f32x4 acc[4] = {};
    const int fr = l & 15, fq = l >> 4;
    float4 va[2][2];

#pragma unroll
    for (int i = 0; i < 2; ++i) {
        va[i][0] = *(const float4*)aptr[i];
        va[i][1] = *(const float4*)(aptr[i] + 4);
    }
#pragma unroll
    for (int i = 0; i < 2; ++i) {
        u16x8 o;
        o[0] = f2bf(va[i][0].x); o[1] = f2bf(va[i][0].y); o[2] = f2bf(va[i][0].z); o[3] = f2bf(va[i][0].w);
        o[4] = f2bf(va[i][1].x); o[5] = f2bf(va[i][1].y); o[6] = f2bf(va[i][1].z); o[7] = f2bf(va[i][1].w);
        *(u16x8*)&Asm[0][awr[i]] = o;
        gload16(bptr[i], &Bsm[0][bbase[i]]);
    }
    __syncthreads();

    int buf = 0;
    for (int kt = 0; kt < 16; ++kt) {
        if (kt < 15) {
#pragma unroll
            for (int i = 0; i < 2; ++i) {
                gload16(bptr[i] + (kt + 1) * 64, &Bsm[buf ^ 1][bbase[i]]);
                va[i][0] = *(const float4*)(aptr[i] + (kt + 1) * 64);
                va[i][1] = *(const float4*)(aptr[i] + (kt + 1) * 64 + 4);
            }
        }
#pragma unroll
        for (int kh = 0; kh < 2; ++kh) {
            int ch = kh * 4 + fq;
            int row = wv * 16 + fr;
            bf16x8 aF = *(const bf16x8*)&Asm[buf][row * 64 + ((ch ^ (row & 7)) << 3)];
            bf16x8 bF[4];
#pragma unroll
            for (int n = 0; n < 4; ++n) {
                int col = n * 16 + fr;
                bF[n] = *(const bf16x8*)&Bsm[buf][col * 64 + ((ch ^ (col & 7)) << 3)];
            }
#pragma unroll
            for (int n = 0; n < 4; ++n)
                acc[n] = __builtin_amdgcn_mfma_f32_16x16x32_bf16(aF, bF[n], acc[n], 0, 0, 0);
        }
        if (kt < 15) {
#pragma unroll
            for (int i = 0; i < 2; ++i) {
                u16x8 o;
                o[0] = f2bf(va[i][0].x); o[1] = f2bf(va[i][0].y); o[2] = f2bf(va[i][0].z); o[3] = f2bf(va[i][0].w);
                o[4] = f2bf(va[i][1].x); o[5] = f2bf(va[i][1].y); o[6] = f2bf(va[i][1].z); o[7] = f2bf(va[i][1].w);
                *(u16x8*)&Asm[buf ^ 1][awr[i]] = o;
            }
        }
        __syncthreads();
        buf ^= 1;
    }

    float* dst = partg + (size_t)blockIdx.y * (NN * EMB);
#pragma unroll
    for (int n = 0; n < 4; ++n) {
        int row0 = rbase + wv * 16 + fq * 4;
        int col = n * 16 + fr;
#pragma unroll
        for (int j = 0; j < 4; ++j)
            dst[(size_t)(row0 + j) * EMB + col] = acc[n][j];
    }
}

__global__ __launch_bounds__(256) void k_gcn2_combine(const float* __restrict__ partg,
                                                      const float* __restrict__ diag,
                                                      const float* __restrict__ q,
                                                      const float* __restrict__ gb2,
                                                      float* __restrict__ h) {
    int tid = threadIdx.x;
    int c = tid & 63;
    int row = blockIdx.x * 4 + (tid >> 6);
    int idx = row * EMB + c;
    float v = gb2[c] - diag[row] * q[idx];
#pragma unroll
    for (int p = 0; p < 8; ++p) v += partg[(size_t)p * NN * EMB + idx];
    v = fmaxf(v, 0.f);
    float mx = v;
#pragma unroll
    for (int m = 32; m >= 1; m >>= 1) mx = fmaxf(mx, __shfl_xor(mx, m));
    float e = expf(v - mx);
    float sum = e;
#pragma unroll
    for (int m = 32; m >= 1; m >>= 1) sum += __shfl_xor(sum, m);
    h[idx] = v - mx - logf(sum);
}

__global__ __launch_bounds__(256) void k_head1_mfma(
    const float* __restrict__ state, const float* __restrict__ h,
    const int* __restrict__ start, const int* __restrict__ end,
    const unsigned short* __restrict__ fw1t, float* __restrict__ part) {
    __shared__ __align__(16) unsigned short Asm[2][64 * 64];
    __shared__ __align__(16) unsigned short Bsm[2][128 * 64];
    __shared__ int ridx[64];
    const int tid = threadIdx.x;
    const int l = tid & 63, wv = tid >> 6;
    const int rbase = blockIdx.x * 64, cbase = blockIdx.y * 128;
    const int ks = blockIdx.z;
    if (tid < 64) ridx[tid] = (ks ? end : start)[rbase + tid];
    __syncthreads();

    const float* aptr[2]; const float* hptr[2]; int awr[2];
#pragma unroll
    for (int i = 0; i < 2; ++i) {
        int slot = i * 256 + tid;
        int r = slot >> 3, cg = slot & 7;
        int gi = ridx[r];
        aptr[i] = state + (size_t)gi * NN + cg * 8;
        hptr[i] = h + gi * EMB + cg * 8;
        awr[i] = r * 64 + ((cg ^ (r & 7)) << 3);
    }
    const unsigned short* bptr[4]; int bbase[4];
#pragma unroll
    for (int i = 0; i < 4; ++i) {
        int n = i * 32 + wv * 8 + (l >> 3);
        int cg = l & 7;
        bptr[i] = fw1t + (size_t)(cbase + n) * 16512 + ((cg ^ (n & 7)) << 3);
        bbase[i] = i * 2048 + wv * 512;
    }

    f32x4 acc[2][4] = {};
    const int wm = wv >> 1, wn = wv & 1;
    const int fr = l & 15, fq = l >> 4;
    float4 va[2][2];

#pragma unroll
    for (int i = 0; i < 2; ++i) {
        va[i][0] = *(const float4*)aptr[i];
        va[i][1] = *(const float4*)(aptr[i] + 4);
    }
#pragma unroll
    for (int i = 0; i < 2; ++i) {
        u16x8 o;
        o[0] = f2bf(va[i][0].x); o[1] = f2bf(va[i][0].y); o[2] = f2bf(va[i][0].z); o[3] = f2bf(va[i][0].w);
        o[4] = f2bf(va[i][1].x); o[5] = f2bf(va[i][1].y); o[6] = f2bf(va[i][1].z); o[7] = f2bf(va[i][1].w);
        *(u16x8*)&Asm[0][awr[i]] = o;
    }
#pragma unroll
    for (int i = 0; i < 4; ++i) gload16(bptr[i] + ks * 8192, &Bsm[0][bbase[i]]);
    __syncthreads();

    int buf = 0;
    for (int kt = 0; kt < 129; ++kt) {
        if (kt < 128) {
            int nxt = kt + 1;
            int kB = (nxt < 128) ? (ks * 8192 + nxt * 64) : (16384 + ks * 64);
#pragma unroll
            for (int i = 0; i < 4; ++i) gload16(bptr[i] + kB, &Bsm[buf ^ 1][bbase[i]]);
#pragma unroll
            for (int i = 0; i < 2; ++i) {
                const float* src = (nxt < 128) ? (aptr[i] + nxt * 64) : hptr[i];
                va[i][0] = *(const float4*)src;
                va[i][1] = *(const float4*)(src + 4);
            }
        }
#pragma unroll
        for (int kh = 0; kh < 2; ++kh) {
            int ch = kh * 4 + fq;
            bf16x8 aF[2], bF[4];
#pragma unroll
            for (int m = 0; m < 2; ++m) {
                int row = wm * 32 + m * 16 + fr;
                aF[m] = *(const bf16x8*)&Asm[buf][row * 64 + ((ch ^ (row & 7)) << 3)];
            }
#pragma unroll
            for (int n = 0; n < 4; ++n) {
                int nl = wn * 64 + n * 16 + fr;
                bF[n] = *(const bf16x8*)&Bsm[buf][nl * 64 + ((ch ^ (nl & 7)) << 3)];
            }
#pragma unroll
            for (int m = 0; m < 2; ++m)
#pragma unroll
                for (int n = 0; n < 4; ++n)
                    acc[m][n] = __builtin_amdgcn_mfma_f32_16x16x32_bf16(
                        aF[m], bF[n], acc[m][n], 0, 0, 0);
        }
        if (kt < 128) {
#pragma unroll
            for (int i = 0; i < 2; ++i) {
                u16x8 o;
                o[0] = f2bf(va[i][0].x); o[1] = f2bf(va[i][0].y); o[2] = f2bf(va[i][0].z); o[3] = f2bf(va[i][0].w);
                o[4] = f2bf(va[i][1].x); o[5] = f2bf(va[i][1].y); o[6] = f2bf(va[i][1].z); o[7] = f2bf(va[i][1].w);
                *(u16x8*)&Asm[buf ^ 1][awr[i]] = o;
            }
        }
        __syncthreads();
        buf ^= 1;
    }

    float* dst = part + (size_t)ks * (NB * H1D);
#pragma unroll
    for (int m = 0; m < 2; ++m) {
        int row0 = rbase + wm * 32 + m * 16 + fq * 4;
#pragma unroll
        for (int n = 0; n < 4; ++n) {
            int col = cbase + wn * 64 + n * 16 + fr;
#pragma unroll
            for (int j = 0; j < 4; ++j)
                dst[(size_t)(row0 + j) * H1D + col] = acc[m][n][j];
        }
    }
}

__global__ void k_head1_fin(const float* __restrict__ part, const float* __restrict__ fb1,
                            float* __restrict__ y1) {
    int i = blockIdx.x * blockDim.x + threadIdx.x;
    float4 a = *(const float4*)&part[(size_t)i * 4];
    float4 b = *(const float4*)&part[(size_t)NB * H1D + (size_t)i * 4];
    float4 bias = *(const float4*)&fb1[(i * 4) & 511];
    float4 o;
    o.x = fmaxf(a.x + b.x + bias.x, 0.f);
    o.y = fmaxf(a.y + b.y + bias.y, 0.f);
    o.z = fmaxf(a.z + b.z + bias.z, 0.f);
    o.w = fmaxf(a.w + b.w + bias.w, 0.f);
    *(float4*)&y1[(size_t)i * 4] = o;
}

// ---- shared 64x64x64 fp32 tile inner product ----
#define GEMM_INNER(AsM, BsM)                                          \
    _Pragma("unroll")                                                 \
    for (int k4 = 0; k4 < 64; k4 += 4) {                              \
        float av[4][4], bv[4][4];                                     \
        _Pragma("unroll")                                             \
        for (int i = 0; i < 4; ++i)                                   \
            *(float4*)av[i] = *(const float4*)&AsM[4 * row_t + i][k4];\
        _Pragma("unroll")                                             \
        for (int t = 0; t < 4; ++t)                                   \
            *(float4*)bv[t] = *(const float4*)&BsM[k4 + t][4 * col_t];\
        _Pragma("unroll")                                             \
        for (int i = 0; i < 4; ++i) {                                 \
            _Pragma("unroll")                                         \
            for (int t = 0; t < 4; ++t) {                             \
                _Pragma("unroll")                                     \
                for (int j = 0; j < 4; ++j)                           \
                    acc[i][j] = fmaf(av[i][t], bv[t][j], acc[i][j]);  \
            }                                                         \
        }                                                             \
    }

// ---------------- K5/K6 (fallback): generic y = relu(A @ W + b) ----------------
__global__ __launch_bounds__(256) void k_gemm_relu(const float* __restrict__ A,
                                                   const float* __restrict__ W,
                                                   const float* __restrict__ bias,
                                                   float* __restrict__ C,
                                                   int M, int N, int K) {
    __shared__ __align__(16) float As[64][68];
    __shared__ __align__(16) float Bs[64][68];
    int tid = threadIdx.x;
    int rbase = blockIdx.x * 64;
    int cbase = blockIdx.y * 64;
    int row_t = tid >> 4, col_t = tid & 15;
    float acc[4][4] = {};
    for (int kt = 0; kt < K / 64; ++kt) {
        int kbase = kt * 64;
#pragma unroll
        for (int l = 0; l < 4; ++l) {
            int lin = l * 256 + tid;
            int r = lin >> 4, k4 = (lin & 15) << 2;
            float4 v = *(const float4*)&A[(size_t)(rbase + r) * K + kbase + k4];
            As[r][k4 + 0] = v.x; As[r][k4 + 1] = v.y; As[r][k4 + 2] = v.z; As[r][k4 + 3] = v.w;
            float4 w = *(const float4*)&W[(size_t)(kbase + r) * N + cbase + k4];
            Bs[r][k4 + 0] = w.x; Bs[r][k4 + 1] = w.y; Bs[r][k4 + 2] = w.z; Bs[r][k4 + 3] = w.w;
        }
        __syncthreads();
        GEMM_INNER(As, Bs)
        __syncthreads();
    }
#pragma unroll
    for (int i = 0; i < 4; ++i) {
        int row = rbase + 4 * row_t + i;
        int col = cbase + 4 * col_t;
        float4 v;
        v.x = fmaxf(acc[i][0] + bias[col + 0], 0.f);
        v.y = fmaxf(acc[i][1] + bias[col + 1], 0.f);
        v.z = fmaxf(acc[i][2] + bias[col + 2], 0.f);
        v.w = fmaxf(acc[i][3] + bias[col + 3], 0.f);
        *(float4*)&C[(size_t)row * N + col] = v;
    }
}

// ---------------- K7: out = relu(y3 @ fw4 + fb4), N=8 ----------------
__global__ void k_head4(const float* __restrict__ y3, const float* __restrict__ fw4,
                        const float* __restrict__ fb4, float* __restrict__ out) {
    int tid = blockIdx.x * blockDim.x + threadIdx.x;
    int b = tid >> 3, j = tid & 7;
    float acc = fb4[j];
    for (int k = 0; k < 128; ++k)
        acc = fmaf(y3[b * 128 + k], fw4[k * 8 + j], acc);
    out[tid] = fmaxf(acc, 0.f);
}

extern "C" void kernel_launch(void* const* d_in, const int* in_sizes, int n_in,
                              void* d_out, int out_size, void* d_ws, size_t ws_size,
                              hipStream_t stream) {
    const float* state = (const float*)d_in[0];
    const int* start   = (const int*)d_in[1];
    const int* end     = (const int*)d_in[2];
    const float* gw1   = (const float*)d_in[3];
    const float* gb1   = (const float*)d_in[4];
    const float* gw2   = (const float*)d_in[5];
    const float* gb2   = (const float*)d_in[6];
    const float* fw1   = (const float*)d_in[7];
    const float* fb1   = (const float*)d_in[8];
    const float* fw2   = (const float*)d_in[9];
    const float* fb2   = (const float*)d_in[10];
    const float* fw3   = (const float*)d_in[11];
    const float* fb3   = (const float*)d_in[12];
    const float* fw4   = (const float*)d_in[13];
    const float* fb4   = (const float*)d_in[14];
    float* out = (float*)d_out;
    float* ws = (float*)d_ws;

    // ---- BIG path layout (floats). Peak 53,084,160 f = 212.3 MB (ws ~1 GB per fill counter). ----
    const size_t NEED_BIG = 53084160ull * 4ull;
    const size_t NEED_FB  = 9748480ull * 4ull;

    if (ws_size >= NEED_BIG) {
        float* diag = ws;
        float* s    = ws + 8192;
        float* q    = ws + 16384;
        unsigned short* qbT = (unsigned short*)(ws + 540672);
        unsigned short* hb  = (unsigned short*)(ws + 802816);
        float* partg = ws + 1064960;
        unsigned short* fw1t = (unsigned short*)(ws + 5259264);
        unsigned short* stateb = (unsigned short*)(ws + 9486336);
        float* parth = ws + 43040768;
        unsigned short* fw2t = (unsigned short*)(ws + 51429376);
        unsigned short* fw3t = (unsigned short*)(ws + 51494912);
        unsigned short* y1b  = (unsigned short*)(ws + 51511296);
        unsigned short* y2b  = (unsigned short*)(ws + 52559872);
        float* y3   = ws + 7356416;

        k_diag<<<32, 256, 0, stream>>>(state, diag);
        k_convert<<<8192, 256, 0, stream>>>(state, diag, stateb, s);
        k_tr_fw1<<<dim3(258, 8), 256, 0, stream>>>(fw1, fw1t);
        k_tr_w<<<dim3(8, 4), 256, 0, stream>>>(fw2, fw2t, 512, 256);
        k_tr_w<<<dim3(4, 2), 256, 0, stream>>>(fw3, fw3t, 256, 128);
        k_q<<<2048, 256, 0, stream>>>(s, gw1, gb1, gw2, q);
        k_tr_q<<<128, 256, 0, stream>>>(q, qbT);
        k_gcn2_mfma_b<<<dim3(128, 8), 256, 0, stream>>>(stateb, qbT, partg);
        k_gcn2_combine_b<<<2048, 256, 0, stream>>>(partg, diag, q, gb2, hb);
        k_head1_mfma_b<<<dim3(32, 4, 4), 256, 0, stream>>>(stateb, hb, start, end, fw1t, parth);
        k_head1_fin4<<<2048, 256, 0, stream>>>(parth, fb1, y1b);
        k_ff1<<<dim3(32, 2), 256, 0, stream>>>(y1b, fw2t, fb2, y2b);
        k_ff2<<<dim3(32, 1), 256, 0, stream>>>(y2b, fw3t, fb3, y3);
        k_head4<<<128, 256, 0, stream>>>(y3, fw4, fb4, out);
        return;
    }

    // ---- FALLBACK: round-3 layout (39 MB) ----
    if (ws_size < NEED_FB) return;

    float* diag = ws;
    float* s    = ws + 8192;
    float* q    = ws + 16384;
    unsigned short* qbT = (unsigned short*)(ws + 540672);
    float* h    = ws + 802816;
    float* partg = ws + 1327104;
    unsigned short* fw1t = (unsigned short*)(ws + 5521408);
    float* parth = ws + 1327104;
    float* y1   = ws + 5521408;
    float* y2   = ws + 16384;
    float* y3   = ws + 7618560;

    k_diag<<<32, 256, 0, stream>>>(state, diag);
    k_tr_fw1<<<dim3(258, 8), 256, 0, stream>>>(fw1, fw1t);
    k_rowdot<<<8192, 256, 0, stream>>>(state, diag, s);
    k_q<<<2048, 256, 0, stream>>>(s, gw1, gb1, gw2, q);
    k_tr_q<<<128, 256, 0, stream>>>(q, qbT);
    k_gcn2_mfma<<<dim3(128, 8), 256, 0, stream>>>(state, qbT, partg);
    k_gcn2_combine<<<2048, 256, 0, stream>>>(partg, diag, q, gb2, h);
    k_head1_mfma<<<dim3(64, 4, 2), 256, 0, stream>>>(state, h, start, end, fw1t, parth);
    k_head1_fin<<<2048, 256, 0, stream>>>(parth, fb1, y1);
    k_gemm_relu<<<dim3(64, 4), 256, 0, stream>>>(y1, fw2, fb2, y2, NB, 256, 512);
    k_gemm_relu<<<dim3(64, 2), 256, 0, stream>>>(y2, fw3, fb3, y3, NB, 128, 256);
    k_head4<<<128, 256, 0, stream>>>(y3, fw4, fb4, out);
}